// Round 1
// 295.685 us; speedup vs baseline: 1.0658x; 1.0658x over previous
//
#include <hip/hip_runtime.h>
#include <stdint.h>

typedef unsigned short u16;
typedef __attribute__((ext_vector_type(8))) short short8;
typedef __attribute__((ext_vector_type(4))) float floatx4;

#define MFMA_BF16 __builtin_amdgcn_mfma_f32_16x16x32_bf16

// dims
#define BB 4
#define TT 2048
#define CC 1024
#define HH 16
#define DH 64
#define MM (BB * TT)      // 8192
#define NQKV (3 * CC)     // 3072

__device__ __forceinline__ u16 f2bf(float f) {
  union { float f; uint32_t u; } un;
  un.f = f;
  uint32_t u = un.u;
  u += 0x7fffu + ((u >> 16) & 1u);   // round-to-nearest-even
  return (u16)(u >> 16);
}

__device__ __forceinline__ uint32_t pk2(float a, float b) {
  return (uint32_t)f2bf(a) | ((uint32_t)f2bf(b) << 16);
}

// pack hi16(a) | hi16(b)<<16 in ONE v_perm_b32 (truncating bf16 round)
__device__ __forceinline__ uint32_t pktrunc(float a, float b) {
  union { float f; uint32_t u; } ua, ub;
  ua.f = a; ub.f = b;
  return __builtin_amdgcn_perm(ub.u, ua.u, 0x07060302u);
}

// async global->LDS, 16B per lane. lds dst = wave-uniform base + lane*16.
__device__ __forceinline__ void gload_lds16(const u16* g, u16* l) {
  __builtin_amdgcn_global_load_lds(
      (const __attribute__((address_space(1))) unsigned int*)g,
      (__attribute__((address_space(3))) unsigned int*)l, 16, 0, 0);
}

// ---------------------------------------------------------------------------
// Kernel 0: fp32 -> bf16 conversions + coalesced weight transpose.
// ---------------------------------------------------------------------------
__global__ __launch_bounds__(256) void convert_kernel(
    const float* __restrict__ x, const float* __restrict__ Wq,
    const float* __restrict__ Wk, const float* __restrict__ Wv,
    const float* __restrict__ Wo, u16* __restrict__ xb,
    u16* __restrict__ Wt, u16* __restrict__ Wob) {
  __shared__ float T[32][33];
  int bid = blockIdx.x, tid = threadIdx.x;
  if (bid < 8192) {
    int i = (bid * 256 + tid) * 4;
    float4 f = *(const float4*)(x + i);
    uint2 o = {pk2(f.x, f.y), pk2(f.z, f.w)};
    *(uint2*)(xb + i) = o;
  } else if (bid < 8192 + 3072) {
    int tb = bid - 8192;
    int sec = tb >> 10, rem = tb & 1023;
    int h = rem >> 6, sub = rem & 63, ct = sub >> 1, dt = sub & 1;
    const float* W = (sec == 0) ? Wq : (sec == 1) ? Wk : Wv;
    int tx = tid & 31, ty = tid >> 5;
#pragma unroll
    for (int p = 0; p < 4; ++p)
      T[ty + 8 * p][tx] =
          W[((size_t)h * CC + ct * 32 + ty + 8 * p) * DH + dt * 32 + tx];
    __syncthreads();
#pragma unroll
    for (int p = 0; p < 4; ++p) {
      int n = sec * 1024 + h * 64 + dt * 32 + ty + 8 * p;
      Wt[(size_t)n * CC + ct * 32 + tx] = f2bf(T[tx][ty + 8 * p]);
    }
  } else {
    int i = ((bid - 11264) * 256 + tid) * 4;
    float4 f = *(const float4*)(Wo + i);
    uint2 o = {pk2(f.x, f.y), pk2(f.z, f.w)};
    *(uint2*)(Wob + i) = o;
  }
}

// ---------------------------------------------------------------------------
// GEMM: C[M,N] = A[M,K] @ Bt[N,K]^T, bf16 in, fp32 accum. m97 pattern.
// MODE 0: q (scaled) / k / v all coalesced [bh][t][d]. MODE 1: +bias fp32.
// ---------------------------------------------------------------------------
template <int MODE>
__global__ __launch_bounds__(256) void gemm_bt(
    const u16* __restrict__ A, const u16* __restrict__ Bt, int M, int N, int K,
    u16* __restrict__ qout, u16* __restrict__ kout, u16* __restrict__ vout,
    float* __restrict__ out, const float* __restrict__ bias) {
  __shared__ u16 As[128][64];  // unpadded: required by global_load_lds
  __shared__ u16 Bs[128][64];
  int tid = threadIdx.x;
  int lane = tid & 63, w = tid >> 6;
  int wm = w >> 1, wn = w & 1;
  int g = lane >> 4, c = lane & 15;
  int m0 = blockIdx.y * 128, n0 = blockIdx.x * 128;

  floatx4 acc[4][4];
#pragma unroll
  for (int i = 0; i < 4; ++i)
#pragma unroll
    for (int j = 0; j < 4; ++j) acc[i][j] = (floatx4){0.f, 0.f, 0.f, 0.f};

  int srow = 32 * w + (lane >> 3);
  int scol = (lane & 7) * 8;
  const u16* Ag = A + (size_t)(m0 + srow) * K + scol;
  const u16* Bg = Bt + (size_t)(n0 + srow) * K + scol;
  u16* AsB = &As[32 * w][0];
  u16* BsB = &Bs[32 * w][0];

  for (int k0 = 0; k0 < K; k0 += 64) {
    __syncthreads();
#pragma unroll
    for (int j = 0; j < 4; ++j)
      gload_lds16(Ag + k0 + (size_t)j * 8 * K, AsB + j * 512);
#pragma unroll
    for (int j = 0; j < 4; ++j)
      gload_lds16(Bg + k0 + (size_t)j * 8 * K, BsB + j * 512);
    __syncthreads();
#pragma unroll
    for (int kc = 0; kc < 2; ++kc) {
      short8 af[4], bfv[4];
#pragma unroll
      for (int mt = 0; mt < 4; ++mt)
        af[mt] = *(const short8*)(&As[wm * 64 + mt * 16 + c][kc * 32 + g * 8]);
#pragma unroll
      for (int nt = 0; nt < 4; ++nt)
        bfv[nt] = *(const short8*)(&Bs[wn * 64 + nt * 16 + c][kc * 32 + g * 8]);
#pragma unroll
      for (int mt = 0; mt < 4; ++mt)
#pragma unroll
        for (int nt = 0; nt < 4; ++nt)
          acc[mt][nt] = MFMA_BF16(af[mt], bfv[nt], acc[mt][nt], 0, 0, 0);
    }
  }

#pragma unroll
  for (int mt = 0; mt < 4; ++mt) {
#pragma unroll
    for (int nt = 0; nt < 4; ++nt) {
#pragma unroll
      for (int r = 0; r < 4; ++r) {
        int m = m0 + wm * 64 + mt * 16 + g * 4 + r;  // C-layout: row=(lane>>4)*4+reg
        int n = n0 + wn * 64 + nt * 16 + c;          //           col=lane&15
        float v = acc[mt][nt][r];
        if (MODE == 0) {
          int b = m >> 11, t = m & 2047;
          int sec = n >> 10, h = (n >> 6) & 15, d = n & 63;
          size_t idx = (((size_t)(b * HH + h)) * TT + t) * DH + d;
          if (sec == 0)
            qout[idx] = f2bf(v * 0.18033688011112042f);
          // ^ DH^-0.5 * log2(e): softmax runs in exp2 domain
          else if (sec == 1)
            kout[idx] = f2bf(v);
          else
            vout[idx] = f2bf(v);  // coalesced; vtrans permutes afterwards
        } else {
          out[(size_t)m * N + n] = v + bias[n];
        }
      }
    }
  }
}

// ---------------------------------------------------------------------------
// V permute-transpose: v[bh][s][d] -> vP[bh][d][tile][u] where
// s = tile*64 + (u&3)*16 + (u>>2)  (i.e. u = 4*(s&15) + ((s>>4)&3)).
// ---------------------------------------------------------------------------
__global__ __launch_bounds__(256) void vtrans(const u16* __restrict__ v,
                                              u16* __restrict__ vP) {
  __shared__ u16 Ld[64][72];
  int tile = blockIdx.x, bh = blockIdx.y, tid = threadIdx.x;
  int row = tid >> 2, col = (tid & 3) * 16;
  const u16* src = v + ((size_t)bh * TT + tile * 64 + row) * DH + col;
  *(uint4*)(&Ld[row][col]) = *(const uint4*)(src);
  *(uint4*)(&Ld[row][col + 8]) = *(const uint4*)(src + 8);
  __syncthreads();
  int d = tid >> 2, u0 = (tid & 3) * 16;
  union { u16 h[16]; uint4 q[2]; } o;
#pragma unroll
  for (int k = 0; k < 16; ++k) {
    int u = u0 + k;
    int s = ((u & 3) << 4) | (u >> 2);
    o.h[k] = Ld[s][d];
  }
  u16* dst = vP + ((size_t)(bh * DH + d)) * TT + tile * 64 + u0;
  *(uint4*)(dst) = o.q[0];
  *(uint4*)(dst + 8) = o.q[1];
}

// ---------------------------------------------------------------------------
// Causal flash with uniform work chunking.
// Because softmax uses NO running max (scale-invariant: the uniform exp2
// scale cancels in sum(p*v)/sum(p)), partials over disjoint key ranges merge
// by PLAIN ADDITION. Heavy q-tiles (x>=8: 18..32 key-tiles) split into two
// equal key-range halves -> 24 chunks/bh, sizes 2..16, launched largest-first
// (LPT): 1536 blocks = 1024 resident + 512 refill, no idle-CU tail.
// Also: lsum via ones-MFMA (kills 32 v_add/tile + epilogue shfl reduce),
// z init via zero C-operand (kills 32 v_mov/tile), SOFTMAX_OFF dropped
// (uniform scale cancels; kills 32 v_sub/tile).
// ---------------------------------------------------------------------------
__constant__ unsigned char CHUNK_X[24] = {15, 15, 7, 14, 14, 13, 13, 6,
                                          12, 12, 11, 11, 5, 10, 10, 9,
                                          9,  4,  8,  8,  3, 2,  1,  0};
__constant__ unsigned char CHUNK_H[24] = {0, 1, 2, 0, 1, 0, 1, 2, 0, 1, 0, 1,
                                          2, 0, 1, 0, 1, 2, 0, 1, 2, 2, 2, 2};

__global__ __launch_bounds__(256, 4) void flash_attn(
    const u16* __restrict__ q, const u16* __restrict__ k,
    const u16* __restrict__ vP, u16* __restrict__ O,
    float* __restrict__ opart, float* __restrict__ lpart) {
  __shared__ u16 Ks[64][72];     // [s][d]
  __shared__ u16 Vs[64][72];     // [d][u]  (u = permuted s)
  __shared__ u16 Ps[4][32][72];  // per-wave P tile [m][u]

  int tid = threadIdx.x;
  int lane = tid & 63, w = tid >> 6;
  int g = lane >> 4, c = lane & 15;

  int id = blockIdx.x;
  int e = id >> 6, bh = id & 63;
  int x = CHUNK_X[e], hf = CHUNK_H[e];  // hf: 0/1 = key-half, 2 = whole tile
  int sb, se;
  if (hf == 2) {
    sb = 0; se = 2 * x + 2;
  } else {
    int n = x + 1; sb = hf * n; se = sb + n;
  }
  int t0 = x << 7;

  const u16* qb = q + (size_t)bh * TT * DH;
  const u16* kb = k + (size_t)bh * TT * DH;
  const u16* vb = vP + (size_t)bh * DH * TT;

  // Q fragments persistent in registers (A-layout: m=lane&15, k=(lane>>4)*8+j)
  short8 qf[2][2];
#pragma unroll
  for (int mt = 0; mt < 2; ++mt) {
    int qrow = t0 + w * 32 + mt * 16 + c;
#pragma unroll
    for (int kc = 0; kc < 2; ++kc)
      qf[mt][kc] = *(const short8*)(qb + (size_t)qrow * DH + kc * 32 + g * 8);
  }

  const floatx4 zf = {0.f, 0.f, 0.f, 0.f};
  const short8 onesf = {(short)0x3F80, (short)0x3F80, (short)0x3F80,
                        (short)0x3F80, (short)0x3F80, (short)0x3F80,
                        (short)0x3F80, (short)0x3F80};  // bf16 1.0 x8

  floatx4 oacc[2][4];
#pragma unroll
  for (int mt = 0; mt < 2; ++mt)
#pragma unroll
    for (int nt = 0; nt < 4; ++nt) oacc[mt][nt] = zf;
  floatx4 lacc[2];
  lacc[0] = zf;
  lacc[1] = zf;

  // staging: row = tid>>2 (0..63), col base = (tid&3)*16, 2x16B per tensor
  int srow = tid >> 2, scol = (tid & 3) * 16;
  const u16* kbase = kb + (size_t)srow * DH + scol;
  const u16* vbase = vb + (size_t)srow * TT + scol;  // vP rows: [d][t-contig]

  // preload iter sb
  uint4 kr0 = *(const uint4*)(kbase + (size_t)(sb << 6) * DH);
  uint4 kr1 = *(const uint4*)(kbase + (size_t)(sb << 6) * DH + 8);
  uint4 vr0 = *(const uint4*)(vbase + (sb << 6));
  uint4 vr1 = *(const uint4*)(vbase + (sb << 6) + 8);

  int nfull = 2 * x;  // iters >= nfull need the causal mask
  int wmax = t0 + w * 32 + 31;
  for (int it = sb; it < se; ++it) {
    int s0 = it << 6;
    __syncthreads();  // all waves done reading prev tiles
    *(uint4*)(&Ks[srow][scol]) = kr0;
    *(uint4*)(&Ks[srow][scol + 8]) = kr1;
    *(uint4*)(&Vs[srow][scol]) = vr0;
    *(uint4*)(&Vs[srow][scol + 8]) = vr1;
    __syncthreads();
    if (it + 1 < se) {  // prefetch next tile: latency hidden by compute
      size_t koff = (size_t)((it + 1) << 6) * DH;
      int voff = (it + 1) << 6;
      kr0 = *(const uint4*)(kbase + koff);
      kr1 = *(const uint4*)(kbase + koff + 8);
      vr0 = *(const uint4*)(vbase + voff);
      vr1 = *(const uint4*)(vbase + voff + 8);
    }
    if (s0 > wmax) continue;  // wave-uniform: tile fully masked (last iter)
    bool masked = (it >= nfull);

    // S = Q K^T ; kf shared across both m-tiles; kc=0 uses zero C-operand
    floatx4 z[2][4];
#pragma unroll
    for (int n = 0; n < 4; ++n) {
      short8 kf = *(const short8*)(&Ks[n * 16 + c][g * 8]);
      z[0][n] = MFMA_BF16(qf[0][0], kf, zf, 0, 0, 0);
      z[1][n] = MFMA_BF16(qf[1][0], kf, zf, 0, 0, 0);
    }
#pragma unroll
    for (int n = 0; n < 4; ++n) {
      short8 kf = *(const short8*)(&Ks[n * 16 + c][32 + g * 8]);
      z[0][n] = MFMA_BF16(qf[0][1], kf, z[0][n], 0, 0, 0);
      z[1][n] = MFMA_BF16(qf[1][1], kf, z[1][n], 0, 0, 0);
    }

    // softmax (no offset: uniform scale cancels in the final division);
    // P packed to bf16 by v_perm truncation, b64 stores
#pragma unroll
    for (int mt = 0; mt < 2; ++mt) {
      int qr = t0 + w * 32 + mt * 16 + g * 4;
#pragma unroll
      for (int r = 0; r < 4; ++r) {
        float p0 = exp2f(z[mt][0][r]);
        float p1 = exp2f(z[mt][1][r]);
        float p2 = exp2f(z[mt][2][r]);
        float p3 = exp2f(z[mt][3][r]);
        if (masked) {
          if (s0 + c > qr + r) p0 = 0.f;
          if (s0 + 16 + c > qr + r) p1 = 0.f;
          if (s0 + 32 + c > qr + r) p2 = 0.f;
          if (s0 + 48 + c > qr + r) p3 = 0.f;
        }
        // u-layout: s = n*16+c -> u = 4c+n; 4 values contiguous at u0=4c
        uint2 pk = {pktrunc(p0, p1), pktrunc(p2, p3)};
        *(uint2*)(&Ps[w][mt * 16 + g * 4 + r][4 * c]) = pk;
      }
    }

    // PV + lsum-by-MFMA: vf shared across both m-tiles (intra-wave LDS)
#pragma unroll
    for (int kc = 0; kc < 2; ++kc) {
      short8 pf0 = *(const short8*)(&Ps[w][c][kc * 32 + g * 8]);
      short8 pf1 = *(const short8*)(&Ps[w][16 + c][kc * 32 + g * 8]);
      lacc[0] = MFMA_BF16(pf0, onesf, lacc[0], 0, 0, 0);
      lacc[1] = MFMA_BF16(pf1, onesf, lacc[1], 0, 0, 0);
#pragma unroll
      for (int nt = 0; nt < 4; ++nt) {
        short8 vf = *(const short8*)(&Vs[nt * 16 + c][kc * 32 + g * 8]);
        oacc[0][nt] = MFMA_BF16(pf0, vf, oacc[0][nt], 0, 0, 0);
        oacc[1][nt] = MFMA_BF16(pf1, vf, oacc[1][nt], 0, 0, 0);
      }
    }
  }

  // epilogue: lacc[mt][r] already holds the full row-sum (replicated over c)
  int b = bh >> 4, h = bh & 15;
  if (hf == 2) {
    // light chunk: normalize and write bf16 directly
#pragma unroll
    for (int mt = 0; mt < 2; ++mt) {
      float inv[4];
#pragma unroll
      for (int r = 0; r < 4; ++r) inv[r] = 1.f / lacc[mt][r];
#pragma unroll
      for (int nt = 0; nt < 4; ++nt)
#pragma unroll
        for (int r = 0; r < 4; ++r) {
          int trow = t0 + w * 32 + mt * 16 + g * 4 + r;
          O[((size_t)b * TT + trow) * CC + h * DH + nt * 16 + c] =
              f2bf(oacc[mt][nt][r] * inv[r]);
        }
    }
  } else {
    // heavy half: store raw fp32 partials; merge_heavy combines
    float* os = opart + ((size_t)hf * 65536 + (size_t)bh * 1024) * 64;
    float* ls = lpart + (size_t)hf * 65536 + (size_t)bh * 1024;
#pragma unroll
    for (int mt = 0; mt < 2; ++mt) {
      int r0 = t0 - 1024 + w * 32 + mt * 16 + g * 4;  // local heavy-row base
#pragma unroll
      for (int nt = 0; nt < 4; ++nt)
#pragma unroll
        for (int r = 0; r < 4; ++r)
          os[(size_t)(r0 + r) * 64 + nt * 16 + c] = oacc[mt][nt][r];
      if (c == 0)
#pragma unroll
        for (int r = 0; r < 4; ++r) ls[r0 + r] = lacc[mt][r];
    }
  }
}

// ---------------------------------------------------------------------------
// Merge the two key-half partials for heavy rows (t in [1024, 2048)):
// Ow = (o0 + o1) / (l0 + l1). ~42 MB traffic, memory-bound.
// ---------------------------------------------------------------------------
__global__ __launch_bounds__(256) void merge_heavy(
    const float* __restrict__ op, const float* __restrict__ lp,
    u16* __restrict__ O) {
  int gid = blockIdx.x * 256 + threadIdx.x;  // 64 bh * 1024 rows * 16 chunks
  int dq = gid & 15;                         // float4 chunk within d=64
  int row = gid >> 4;                        // bh*1024 + lr
  float4 a = *(const float4*)(op + (size_t)row * 64 + dq * 4);
  float4 b = *(const float4*)(op + ((size_t)row + 65536) * 64 + dq * 4);
  float inv = 1.f / (lp[row] + lp[row + 65536]);
  int bh = row >> 10, lr = row & 1023;
  int bb = bh >> 4, h = bh & 15;
  u16* dst = O + ((size_t)bb * TT + 1024 + lr) * CC + h * DH + dq * 4;
  uint2 o = {pk2((a.x + b.x) * inv, (a.y + b.y) * inv),
             pk2((a.z + b.z) * inv, (a.w + b.w) * inv)};
  *(uint2*)dst = o;
}

// ---------------------------------------------------------------------------
extern "C" void kernel_launch(void* const* d_in, const int* in_sizes, int n_in,
                              void* d_out, int out_size, void* d_ws,
                              size_t ws_size, hipStream_t stream) {
  const float* x = (const float*)d_in[0];
  const float* Wq = (const float*)d_in[1];
  const float* Wk = (const float*)d_in[2];
  const float* Wv = (const float*)d_in[3];
  const float* Wo = (const float*)d_in[4];
  const float* bo = (const float*)d_in[5];
  float* out = (float*)d_out;

  u16* ws = (u16*)d_ws;
  u16* xb = ws;                        // 8388608  (reused as Ow after QKV GEMM)
  u16* Wt = xb + 8388608;              // 3145728  (dead after gemm<0>: lpart)
  u16* Wob = Wt + 3145728;             // 1048576
  u16* qw = Wob + 1048576;             // 8388608
  u16* kw = qw + 8388608;              // 8388608
  u16* vw = kw + 8388608;              // 8388608 ([bh][t][d], coalesced)
  u16* vP = vw + 8388608;              // 8388608 (permuted [bh][d][tile][u])
  u16* Ow = xb;                        // alias: xb dead after gemm_bt<0>
  // partial buffers: d_out (33.55 MB fp32, dead until gemm<1>) holds the two
  // oacc half-slots exactly; lsum halves (512 KB) live in the dead Wt region.
  float* opart = (float*)d_out;
  float* lpart = (float*)Wt;

  convert_kernel<<<12288, 256, 0, stream>>>(x, Wq, Wk, Wv, Wo, xb, Wt, Wob);

  gemm_bt<0><<<dim3(NQKV / 128, MM / 128), 256, 0, stream>>>(
      xb, Wt, MM, NQKV, CC, qw, kw, vw, nullptr, nullptr);

  vtrans<<<dim3(TT / 64, BB * HH), 256, 0, stream>>>(vw, vP);

  flash_attn<<<dim3(1536), 256, 0, stream>>>(qw, kw, vP, Ow, opart, lpart);

  merge_heavy<<<dim3(4096), 256, 0, stream>>>(opart, lpart, Ow);

  gemm_bt<1><<<dim3(CC / 128, MM / 128), 256, 0, stream>>>(
      Ow, Wob, MM, CC, CC, nullptr, nullptr, nullptr, out, bo);
}

// Round 2
// 281.042 us; speedup vs baseline: 1.1213x; 1.0521x over previous
//
#include <hip/hip_runtime.h>
#include <stdint.h>

typedef unsigned short u16;
typedef __attribute__((ext_vector_type(8))) short short8;
typedef __attribute__((ext_vector_type(4))) float floatx4;

#define MFMA_BF16 __builtin_amdgcn_mfma_f32_16x16x32_bf16

// dims
#define BB 4
#define TT 2048
#define CC 1024
#define HH 16
#define DH 64
#define MM (BB * TT)      // 8192
#define NQKV (3 * CC)     // 3072

__device__ __forceinline__ u16 f2bf(float f) {
  union { float f; uint32_t u; } un;
  un.f = f;
  uint32_t u = un.u;
  u += 0x7fffu + ((u >> 16) & 1u);   // round-to-nearest-even
  return (u16)(u >> 16);
}

__device__ __forceinline__ uint32_t pk2(float a, float b) {
  return (uint32_t)f2bf(a) | ((uint32_t)f2bf(b) << 16);
}

// pack hi16(a) | hi16(b)<<16 in ONE v_perm_b32 (truncating bf16 round)
__device__ __forceinline__ uint32_t pktrunc(float a, float b) {
  union { float f; uint32_t u; } ua, ub;
  ua.f = a; ub.f = b;
  return __builtin_amdgcn_perm(ub.u, ua.u, 0x07060302u);
}

// async global->LDS, 16B per lane. lds dst = wave-uniform base + lane*16.
__device__ __forceinline__ void gload_lds16(const u16* g, u16* l) {
  __builtin_amdgcn_global_load_lds(
      (const __attribute__((address_space(1))) unsigned int*)g,
      (__attribute__((address_space(3))) unsigned int*)l, 16, 0, 0);
}

// ---------------------------------------------------------------------------
// Kernel 0: fp32 -> bf16 conversions + coalesced weight transpose.
// ---------------------------------------------------------------------------
__global__ __launch_bounds__(256) void convert_kernel(
    const float* __restrict__ x, const float* __restrict__ Wq,
    const float* __restrict__ Wk, const float* __restrict__ Wv,
    const float* __restrict__ Wo, u16* __restrict__ xb,
    u16* __restrict__ Wt, u16* __restrict__ Wob) {
  __shared__ float T[32][33];
  int bid = blockIdx.x, tid = threadIdx.x;
  if (bid < 8192) {
    int i = (bid * 256 + tid) * 4;
    float4 f = *(const float4*)(x + i);
    uint2 o = {pk2(f.x, f.y), pk2(f.z, f.w)};
    *(uint2*)(xb + i) = o;
  } else if (bid < 8192 + 3072) {
    int tb = bid - 8192;
    int sec = tb >> 10, rem = tb & 1023;
    int h = rem >> 6, sub = rem & 63, ct = sub >> 1, dt = sub & 1;
    const float* W = (sec == 0) ? Wq : (sec == 1) ? Wk : Wv;
    int tx = tid & 31, ty = tid >> 5;
#pragma unroll
    for (int p = 0; p < 4; ++p)
      T[ty + 8 * p][tx] =
          W[((size_t)h * CC + ct * 32 + ty + 8 * p) * DH + dt * 32 + tx];
    __syncthreads();
#pragma unroll
    for (int p = 0; p < 4; ++p) {
      int n = sec * 1024 + h * 64 + dt * 32 + ty + 8 * p;
      Wt[(size_t)n * CC + ct * 32 + tx] = f2bf(T[tx][ty + 8 * p]);
    }
  } else {
    int i = ((bid - 11264) * 256 + tid) * 4;
    float4 f = *(const float4*)(Wo + i);
    uint2 o = {pk2(f.x, f.y), pk2(f.z, f.w)};
    *(uint2*)(Wob + i) = o;
  }
}

// ---------------------------------------------------------------------------
// QKV GEMM, deep-pipelined: C[8192,3072] = xb[8192,1024] @ Wt[3072,1024]^T.
// BM=256 BN=384 BK=32, 512 thr = 8 waves (2M x 4N), per-wave 128x96.
// Grid 32x8 = 256 blocks = exactly 1/CU, single round (perfect balance).
// 64B LDS rows (BK=32) make the fragment read pattern bank-conflict-minimal
// WITHOUT swizzle (row parity enters the bank index).  Double-buffered LDS;
// next tile's global_load_lds issued BEFORE compute, vmcnt(0) waits on loads
// aged by a full iteration (~0 stall), ONE raw s_barrier per K-tile.
// Staging into buf[p^1] during compute of buf[p] is safe: buf[p^1]'s last
// readers finished before the previous barrier.
// ---------------------------------------------------------------------------
__global__ __launch_bounds__(512, 2) void gemm_qkv(
    const u16* __restrict__ A, const u16* __restrict__ Bt,
    u16* __restrict__ qout, u16* __restrict__ kout, u16* __restrict__ vout) {
  __shared__ u16 As[2 * 256 * 32];  // 32 KB (two 16KB slots)
  __shared__ u16 Bs[2 * 384 * 32];  // 48 KB (two 24KB slots)

  int tid = threadIdx.x;
  int lane = tid & 63, w = tid >> 6;
  int wr = w >> 2, wc = w & 3;
  int g = lane >> 4, c = lane & 15;
  int m0 = blockIdx.y * 256, n0 = blockIdx.x * 384;

  floatx4 acc[8][6];
#pragma unroll
  for (int i = 0; i < 8; ++i)
#pragma unroll
    for (int j = 0; j < 6; ++j) acc[i][j] = (floatx4){0.f, 0.f, 0.f, 0.f};

  // staging: thread -> (row = tid>>2 [+128*j], col = (tid&3)*8); LDS linear.
  int arow = tid >> 2, acol = (tid & 3) * 8;
  const u16* Ag = A + (size_t)(m0 + arow) * CC + acol;
  const u16* Bg = Bt + (size_t)(n0 + arow) * CC + acol;
  u16* asd = As + tid * 8;
  u16* bsd = Bs + tid * 8;

  // fragment-read bases (per-thread invariant)
  const u16* Asr = As + (wr * 128 + c) * 32 + g * 8;
  const u16* Bsr = Bs + (wc * 96 + c) * 32 + g * 8;

  // prologue: stage tile 0 into slot 0
  gload_lds16(Ag, asd);
  gload_lds16(Ag + (size_t)128 * CC, asd + 4096);
  gload_lds16(Bg, bsd);
  gload_lds16(Bg + (size_t)128 * CC, bsd + 4096);
  gload_lds16(Bg + (size_t)256 * CC, bsd + 8192);
  asm volatile("s_waitcnt vmcnt(0)" ::: "memory");
  __builtin_amdgcn_s_barrier();
  asm volatile("" ::: "memory");

#define GEMM_ITER(p, t)                                                       \
  {                                                                           \
    if ((t) + 1 < 32) { /* stage tile t+1 into slot p^1 (free since t-1) */   \
      size_t ko = (size_t)((t) + 1) * 32;                                     \
      gload_lds16(Ag + ko, asd + ((p) ^ 1) * 8192);                           \
      gload_lds16(Ag + ko + (size_t)128 * CC, asd + ((p) ^ 1) * 8192 + 4096); \
      gload_lds16(Bg + ko, bsd + ((p) ^ 1) * 12288);                          \
      gload_lds16(Bg + ko + (size_t)128 * CC, bsd + ((p) ^ 1) * 12288 + 4096);\
      gload_lds16(Bg + ko + (size_t)256 * CC, bsd + ((p) ^ 1) * 12288 + 8192);\
    }                                                                         \
    short8 bfr[6];                                                            \
    _Pragma("unroll") for (int nt = 0; nt < 6; ++nt)                          \
        bfr[nt] = *(const short8*)(Bsr + (p) * 12288 + nt * 512);             \
    __builtin_amdgcn_s_setprio(1);                                            \
    _Pragma("unroll") for (int mt = 0; mt < 8; ++mt) {                        \
      short8 af = *(const short8*)(Asr + (p) * 8192 + mt * 512);              \
      _Pragma("unroll") for (int nt = 0; nt < 6; ++nt)                        \
          acc[mt][nt] = MFMA_BF16(af, bfr[nt], acc[mt][nt], 0, 0, 0);         \
    }                                                                         \
    __builtin_amdgcn_s_setprio(0);                                            \
    asm volatile("s_waitcnt vmcnt(0)" ::: "memory"); /* aged a full iter */   \
    __builtin_amdgcn_s_barrier();                                             \
    asm volatile("" ::: "memory");                                            \
  }

#pragma unroll 1
  for (int tt = 0; tt < 16; ++tt) {
    GEMM_ITER(0, 2 * tt);
    GEMM_ITER(1, 2 * tt + 1);
  }
#undef GEMM_ITER

  // epilogue: scatter to q/k/v in [bh][t][d] layout (16-lane d-contiguous)
  int mrow = m0 + wr * 128 + g * 4;
  int ncol = n0 + wc * 96 + c;
#pragma unroll
  for (int nt = 0; nt < 6; ++nt) {
    int n = ncol + nt * 16;
    int sec = n >> 10, h = (n >> 6) & 15, d = n & 63;
    u16* dst = (sec == 0) ? qout : (sec == 1) ? kout : vout;
    float sc = (sec == 0) ? 0.18033688011112042f : 1.f;
    // ^ DH^-0.5 * log2(e): softmax runs in exp2 domain
#pragma unroll
    for (int mt = 0; mt < 8; ++mt) {
#pragma unroll
      for (int r = 0; r < 4; ++r) {
        int m = mrow + mt * 16 + r;
        int b = m >> 11, t = m & 2047;
        dst[(((size_t)(b * HH + h)) * TT + t) * DH + d] =
            f2bf(acc[mt][nt][r] * sc);
      }
    }
  }
}

// ---------------------------------------------------------------------------
// GEMM: C[M,N] = A[M,K] @ Bt[N,K]^T, bf16 in, fp32 accum. m97 pattern.
// (now used only as MODE 1: output projection +bias fp32)
// ---------------------------------------------------------------------------
template <int MODE>
__global__ __launch_bounds__(256) void gemm_bt(
    const u16* __restrict__ A, const u16* __restrict__ Bt, int M, int N, int K,
    u16* __restrict__ qout, u16* __restrict__ kout, u16* __restrict__ vout,
    float* __restrict__ out, const float* __restrict__ bias) {
  __shared__ u16 As[128][64];  // unpadded: required by global_load_lds
  __shared__ u16 Bs[128][64];
  int tid = threadIdx.x;
  int lane = tid & 63, w = tid >> 6;
  int wm = w >> 1, wn = w & 1;
  int g = lane >> 4, c = lane & 15;
  int m0 = blockIdx.y * 128, n0 = blockIdx.x * 128;

  floatx4 acc[4][4];
#pragma unroll
  for (int i = 0; i < 4; ++i)
#pragma unroll
    for (int j = 0; j < 4; ++j) acc[i][j] = (floatx4){0.f, 0.f, 0.f, 0.f};

  int srow = 32 * w + (lane >> 3);
  int scol = (lane & 7) * 8;
  const u16* Ag = A + (size_t)(m0 + srow) * K + scol;
  const u16* Bg = Bt + (size_t)(n0 + srow) * K + scol;
  u16* AsB = &As[32 * w][0];
  u16* BsB = &Bs[32 * w][0];

  for (int k0 = 0; k0 < K; k0 += 64) {
    __syncthreads();
#pragma unroll
    for (int j = 0; j < 4; ++j)
      gload_lds16(Ag + k0 + (size_t)j * 8 * K, AsB + j * 512);
#pragma unroll
    for (int j = 0; j < 4; ++j)
      gload_lds16(Bg + k0 + (size_t)j * 8 * K, BsB + j * 512);
    __syncthreads();
#pragma unroll
    for (int kc = 0; kc < 2; ++kc) {
      short8 af[4], bfv[4];
#pragma unroll
      for (int mt = 0; mt < 4; ++mt)
        af[mt] = *(const short8*)(&As[wm * 64 + mt * 16 + c][kc * 32 + g * 8]);
#pragma unroll
      for (int nt = 0; nt < 4; ++nt)
        bfv[nt] = *(const short8*)(&Bs[wn * 64 + nt * 16 + c][kc * 32 + g * 8]);
#pragma unroll
      for (int mt = 0; mt < 4; ++mt)
#pragma unroll
        for (int nt = 0; nt < 4; ++nt)
          acc[mt][nt] = MFMA_BF16(af[mt], bfv[nt], acc[mt][nt], 0, 0, 0);
    }
  }

#pragma unroll
  for (int mt = 0; mt < 4; ++mt) {
#pragma unroll
    for (int nt = 0; nt < 4; ++nt) {
#pragma unroll
      for (int r = 0; r < 4; ++r) {
        int m = m0 + wm * 64 + mt * 16 + g * 4 + r;  // C-layout: row=(lane>>4)*4+reg
        int n = n0 + wn * 64 + nt * 16 + c;          //           col=lane&15
        float v = acc[mt][nt][r];
        if (MODE == 0) {
          int b = m >> 11, t = m & 2047;
          int sec = n >> 10, h = (n >> 6) & 15, d = n & 63;
          size_t idx = (((size_t)(b * HH + h)) * TT + t) * DH + d;
          if (sec == 0)
            qout[idx] = f2bf(v * 0.18033688011112042f);
          else if (sec == 1)
            kout[idx] = f2bf(v);
          else
            vout[idx] = f2bf(v);
        } else {
          out[(size_t)m * N + n] = v + bias[n];
        }
      }
    }
  }
}

// ---------------------------------------------------------------------------
// V permute-transpose: v[bh][s][d] -> vP[bh][d][tile][u] where
// s = tile*64 + (u&3)*16 + (u>>2)  (i.e. u = 4*(s&15) + ((s>>4)&3)).
// ---------------------------------------------------------------------------
__global__ __launch_bounds__(256) void vtrans(const u16* __restrict__ v,
                                              u16* __restrict__ vP) {
  __shared__ u16 Ld[64][72];
  int tile = blockIdx.x, bh = blockIdx.y, tid = threadIdx.x;
  int row = tid >> 2, col = (tid & 3) * 16;
  const u16* src = v + ((size_t)bh * TT + tile * 64 + row) * DH + col;
  *(uint4*)(&Ld[row][col]) = *(const uint4*)(src);
  *(uint4*)(&Ld[row][col + 8]) = *(const uint4*)(src + 8);
  __syncthreads();
  int d = tid >> 2, u0 = (tid & 3) * 16;
  union { u16 h[16]; uint4 q[2]; } o;
#pragma unroll
  for (int k = 0; k < 16; ++k) {
    int u = u0 + k;
    int s = ((u & 3) << 4) | (u >> 2);
    o.h[k] = Ld[s][d];
  }
  u16* dst = vP + ((size_t)(bh * DH + d)) * TT + tile * 64 + u0;
  *(uint4*)(dst) = o.q[0];
  *(uint4*)(dst + 8) = o.q[1];
}

// ---------------------------------------------------------------------------
// Causal flash with uniform work chunking (LPT order, split heavy q-tiles
// into two key-halves; scale-free softmax partials merge by plain addition).
// ---------------------------------------------------------------------------
__constant__ unsigned char CHUNK_X[24] = {15, 15, 7, 14, 14, 13, 13, 6,
                                          12, 12, 11, 11, 5, 10, 10, 9,
                                          9,  4,  8,  8,  3, 2,  1,  0};
__constant__ unsigned char CHUNK_H[24] = {0, 1, 2, 0, 1, 0, 1, 2, 0, 1, 0, 1,
                                          2, 0, 1, 0, 1, 2, 0, 1, 2, 2, 2, 2};

__global__ __launch_bounds__(256, 4) void flash_attn(
    const u16* __restrict__ q, const u16* __restrict__ k,
    const u16* __restrict__ vP, u16* __restrict__ O,
    float* __restrict__ opart, float* __restrict__ lpart) {
  __shared__ u16 Ks[64][72];     // [s][d]
  __shared__ u16 Vs[64][72];     // [d][u]  (u = permuted s)
  __shared__ u16 Ps[4][32][72];  // per-wave P tile [m][u]

  int tid = threadIdx.x;
  int lane = tid & 63, w = tid >> 6;
  int g = lane >> 4, c = lane & 15;

  int id = blockIdx.x;
  int e = id >> 6, bh = id & 63;
  int x = CHUNK_X[e], hf = CHUNK_H[e];  // hf: 0/1 = key-half, 2 = whole tile
  int sb, se;
  if (hf == 2) {
    sb = 0; se = 2 * x + 2;
  } else {
    int n = x + 1; sb = hf * n; se = sb + n;
  }
  int t0 = x << 7;

  const u16* qb = q + (size_t)bh * TT * DH;
  const u16* kb = k + (size_t)bh * TT * DH;
  const u16* vb = vP + (size_t)bh * DH * TT;

  // Q fragments persistent in registers (A-layout: m=lane&15, k=(lane>>4)*8+j)
  short8 qf[2][2];
#pragma unroll
  for (int mt = 0; mt < 2; ++mt) {
    int qrow = t0 + w * 32 + mt * 16 + c;
#pragma unroll
    for (int kc = 0; kc < 2; ++kc)
      qf[mt][kc] = *(const short8*)(qb + (size_t)qrow * DH + kc * 32 + g * 8);
  }

  const floatx4 zf = {0.f, 0.f, 0.f, 0.f};
  const short8 onesf = {(short)0x3F80, (short)0x3F80, (short)0x3F80,
                        (short)0x3F80, (short)0x3F80, (short)0x3F80,
                        (short)0x3F80, (short)0x3F80};  // bf16 1.0 x8

  floatx4 oacc[2][4];
#pragma unroll
  for (int mt = 0; mt < 2; ++mt)
#pragma unroll
    for (int nt = 0; nt < 4; ++nt) oacc[mt][nt] = zf;
  floatx4 lacc[2];
  lacc[0] = zf;
  lacc[1] = zf;

  // staging: row = tid>>2 (0..63), col base = (tid&3)*16, 2x16B per tensor
  int srow = tid >> 2, scol = (tid & 3) * 16;
  const u16* kbase = kb + (size_t)srow * DH + scol;
  const u16* vbase = vb + (size_t)srow * TT + scol;  // vP rows: [d][t-contig]

  // preload iter sb
  uint4 kr0 = *(const uint4*)(kbase + (size_t)(sb << 6) * DH);
  uint4 kr1 = *(const uint4*)(kbase + (size_t)(sb << 6) * DH + 8);
  uint4 vr0 = *(const uint4*)(vbase + (sb << 6));
  uint4 vr1 = *(const uint4*)(vbase + (sb << 6) + 8);

  int nfull = 2 * x;  // iters >= nfull need the causal mask
  int wmax = t0 + w * 32 + 31;
  for (int it = sb; it < se; ++it) {
    int s0 = it << 6;
    __syncthreads();  // all waves done reading prev tiles
    *(uint4*)(&Ks[srow][scol]) = kr0;
    *(uint4*)(&Ks[srow][scol + 8]) = kr1;
    *(uint4*)(&Vs[srow][scol]) = vr0;
    *(uint4*)(&Vs[srow][scol + 8]) = vr1;
    __syncthreads();
    if (it + 1 < se) {  // prefetch next tile: latency hidden by compute
      size_t koff = (size_t)((it + 1) << 6) * DH;
      int voff = (it + 1) << 6;
      kr0 = *(const uint4*)(kbase + koff);
      kr1 = *(const uint4*)(kbase + koff + 8);
      vr0 = *(const uint4*)(vbase + voff);
      vr1 = *(const uint4*)(vbase + voff + 8);
    }
    if (s0 > wmax) continue;  // wave-uniform: tile fully masked (last iter)
    bool masked = (it >= nfull);

    // S = Q K^T ; kf shared across both m-tiles; kc=0 uses zero C-operand
    floatx4 z[2][4];
#pragma unroll
    for (int n = 0; n < 4; ++n) {
      short8 kf = *(const short8*)(&Ks[n * 16 + c][g * 8]);
      z[0][n] = MFMA_BF16(qf[0][0], kf, zf, 0, 0, 0);
      z[1][n] = MFMA_BF16(qf[1][0], kf, zf, 0, 0, 0);
    }
#pragma unroll
    for (int n = 0; n < 4; ++n) {
      short8 kf = *(const short8*)(&Ks[n * 16 + c][32 + g * 8]);
      z[0][n] = MFMA_BF16(qf[0][1], kf, z[0][n], 0, 0, 0);
      z[1][n] = MFMA_BF16(qf[1][1], kf, z[1][n], 0, 0, 0);
    }

    // softmax (no offset: uniform scale cancels in the final division);
    // P packed to bf16 by v_perm truncation, b64 stores
#pragma unroll
    for (int mt = 0; mt < 2; ++mt) {
      int qr = t0 + w * 32 + mt * 16 + g * 4;
#pragma unroll
      for (int r = 0; r < 4; ++r) {
        float p0 = exp2f(z[mt][0][r]);
        float p1 = exp2f(z[mt][1][r]);
        float p2 = exp2f(z[mt][2][r]);
        float p3 = exp2f(z[mt][3][r]);
        if (masked) {
          if (s0 + c > qr + r) p0 = 0.f;
          if (s0 + 16 + c > qr + r) p1 = 0.f;
          if (s0 + 32 + c > qr + r) p2 = 0.f;
          if (s0 + 48 + c > qr + r) p3 = 0.f;
        }
        // u-layout: s = n*16+c -> u = 4c+n; 4 values contiguous at u0=4c
        uint2 pk = {pktrunc(p0, p1), pktrunc(p2, p3)};
        *(uint2*)(&Ps[w][mt * 16 + g * 4 + r][4 * c]) = pk;
      }
    }

    // PV + lsum-by-MFMA: vf shared across both m-tiles (intra-wave LDS)
#pragma unroll
    for (int kc = 0; kc < 2; ++kc) {
      short8 pf0 = *(const short8*)(&Ps[w][c][kc * 32 + g * 8]);
      short8 pf1 = *(const short8*)(&Ps[w][16 + c][kc * 32 + g * 8]);
      lacc[0] = MFMA_BF16(pf0, onesf, lacc[0], 0, 0, 0);
      lacc[1] = MFMA_BF16(pf1, onesf, lacc[1], 0, 0, 0);
#pragma unroll
      for (int nt = 0; nt < 4; ++nt) {
        short8 vf = *(const short8*)(&Vs[nt * 16 + c][kc * 32 + g * 8]);
        oacc[0][nt] = MFMA_BF16(pf0, vf, oacc[0][nt], 0, 0, 0);
        oacc[1][nt] = MFMA_BF16(pf1, vf, oacc[1][nt], 0, 0, 0);
      }
    }
  }

  // epilogue: lacc[mt][r] already holds the full row-sum (replicated over c)
  int b = bh >> 4, h = bh & 15;
  if (hf == 2) {
    // light chunk: normalize and write bf16 directly
#pragma unroll
    for (int mt = 0; mt < 2; ++mt) {
      float inv[4];
#pragma unroll
      for (int r = 0; r < 4; ++r) inv[r] = 1.f / lacc[mt][r];
#pragma unroll
      for (int nt = 0; nt < 4; ++nt)
#pragma unroll
        for (int r = 0; r < 4; ++r) {
          int trow = t0 + w * 32 + mt * 16 + g * 4 + r;
          O[((size_t)b * TT + trow) * CC + h * DH + nt * 16 + c] =
              f2bf(oacc[mt][nt][r] * inv[r]);
        }
    }
  } else {
    // heavy half: store raw fp32 partials; merge_heavy combines
    float* os = opart + ((size_t)hf * 65536 + (size_t)bh * 1024) * 64;
    float* ls = lpart + (size_t)hf * 65536 + (size_t)bh * 1024;
#pragma unroll
    for (int mt = 0; mt < 2; ++mt) {
      int r0 = t0 - 1024 + w * 32 + mt * 16 + g * 4;  // local heavy-row base
#pragma unroll
      for (int nt = 0; nt < 4; ++nt)
#pragma unroll
        for (int r = 0; r < 4; ++r)
          os[(size_t)(r0 + r) * 64 + nt * 16 + c] = oacc[mt][nt][r];
      if (c == 0)
#pragma unroll
        for (int r = 0; r < 4; ++r) ls[r0 + r] = lacc[mt][r];
    }
  }
}

// ---------------------------------------------------------------------------
// Merge the two key-half partials for heavy rows (t in [1024, 2048)):
// Ow = (o0 + o1) / (l0 + l1). ~42 MB traffic, memory-bound.
// ---------------------------------------------------------------------------
__global__ __launch_bounds__(256) void merge_heavy(
    const float* __restrict__ op, const float* __restrict__ lp,
    u16* __restrict__ O) {
  int gid = blockIdx.x * 256 + threadIdx.x;  // 64 bh * 1024 rows * 16 chunks
  int dq = gid & 15;                         // float4 chunk within d=64
  int row = gid >> 4;                        // bh*1024 + lr
  float4 a = *(const float4*)(op + (size_t)row * 64 + dq * 4);
  float4 b = *(const float4*)(op + ((size_t)row + 65536) * 64 + dq * 4);
  float inv = 1.f / (lp[row] + lp[row + 65536]);
  int bh = row >> 10, lr = row & 1023;
  int bb = bh >> 4, h = bh & 15;
  u16* dst = O + ((size_t)bb * TT + 1024 + lr) * CC + h * DH + dq * 4;
  uint2 o = {pk2((a.x + b.x) * inv, (a.y + b.y) * inv),
             pk2((a.z + b.z) * inv, (a.w + b.w) * inv)};
  *(uint2*)dst = o;
}

// ---------------------------------------------------------------------------
extern "C" void kernel_launch(void* const* d_in, const int* in_sizes, int n_in,
                              void* d_out, int out_size, void* d_ws,
                              size_t ws_size, hipStream_t stream) {
  const float* x = (const float*)d_in[0];
  const float* Wq = (const float*)d_in[1];
  const float* Wk = (const float*)d_in[2];
  const float* Wv = (const float*)d_in[3];
  const float* Wo = (const float*)d_in[4];
  const float* bo = (const float*)d_in[5];
  float* out = (float*)d_out;

  u16* ws = (u16*)d_ws;
  u16* xb = ws;                        // 8388608  (reused as Ow after QKV GEMM)
  u16* Wt = xb + 8388608;              // 3145728  (dead after gemm<0>: lpart)
  u16* Wob = Wt + 3145728;             // 1048576
  u16* qw = Wob + 1048576;             // 8388608
  u16* kw = qw + 8388608;              // 8388608
  u16* vw = kw + 8388608;              // 8388608 ([bh][t][d], coalesced)
  u16* vP = vw + 8388608;              // 8388608 (permuted [bh][d][tile][u])
  u16* Ow = xb;                        // alias: xb dead after gemm_qkv
  float* opart = (float*)d_out;        // dead until gemm<1>
  float* lpart = (float*)Wt;           // Wt dead after gemm_qkv

  convert_kernel<<<12288, 256, 0, stream>>>(x, Wq, Wk, Wv, Wo, xb, Wt, Wob);

  gemm_qkv<<<dim3(NQKV / 384, MM / 256), 512, 0, stream>>>(
      xb, Wt, qw, kw, vw);

  vtrans<<<dim3(TT / 64, BB * HH), 256, 0, stream>>>(vw, vP);

  flash_attn<<<dim3(1536), 256, 0, stream>>>(qw, kw, vP, Ow, opart, lpart);

  merge_heavy<<<dim3(4096), 256, 0, stream>>>(opart, lpart, Ow);

  gemm_bt<1><<<dim3(CC / 128, MM / 128), 256, 0, stream>>>(
      Ow, Wob, MM, CC, CC, nullptr, nullptr, nullptr, out, bo);
}

// Round 3
// 280.333 us; speedup vs baseline: 1.1241x; 1.0025x over previous
//
#include <hip/hip_runtime.h>
#include <stdint.h>

typedef unsigned short u16;
typedef __attribute__((ext_vector_type(8))) short short8;
typedef __attribute__((ext_vector_type(4))) float floatx4;

#define MFMA_BF16 __builtin_amdgcn_mfma_f32_16x16x32_bf16

// dims
#define BB 4
#define TT 2048
#define CC 1024
#define HH 16
#define DH 64
#define MM (BB * TT)      // 8192
#define NQKV (3 * CC)     // 3072

__device__ __forceinline__ u16 f2bf(float f) {
  union { float f; uint32_t u; } un;
  un.f = f;
  uint32_t u = un.u;
  u += 0x7fffu + ((u >> 16) & 1u);   // round-to-nearest-even
  return (u16)(u >> 16);
}

__device__ __forceinline__ uint32_t pk2(float a, float b) {
  return (uint32_t)f2bf(a) | ((uint32_t)f2bf(b) << 16);
}

// pack hi16(a) | hi16(b)<<16 in ONE v_perm_b32 (truncating bf16 round)
__device__ __forceinline__ uint32_t pktrunc(float a, float b) {
  union { float f; uint32_t u; } ua, ub;
  ua.f = a; ub.f = b;
  return __builtin_amdgcn_perm(ub.u, ua.u, 0x07060302u);
}

// async global->LDS, 16B per lane. lds dst = wave-uniform base + lane*16.
__device__ __forceinline__ void gload_lds16(const u16* g, u16* l) {
  __builtin_amdgcn_global_load_lds(
      (const __attribute__((address_space(1))) unsigned int*)g,
      (__attribute__((address_space(3))) unsigned int*)l, 16, 0, 0);
}

// raw barrier with compiler-level memory fence (no vmcnt/lgkm drain)
__device__ __forceinline__ void BAR() {
  asm volatile("" ::: "memory");
  __builtin_amdgcn_s_barrier();
  asm volatile("" ::: "memory");
}

// ---------------------------------------------------------------------------
// Kernel 0: fp32 -> bf16 conversions + coalesced weight transpose.
// ---------------------------------------------------------------------------
__global__ __launch_bounds__(256) void convert_kernel(
    const float* __restrict__ x, const float* __restrict__ Wq,
    const float* __restrict__ Wk, const float* __restrict__ Wv,
    const float* __restrict__ Wo, u16* __restrict__ xb,
    u16* __restrict__ Wt, u16* __restrict__ Wob) {
  __shared__ float T[32][33];
  int bid = blockIdx.x, tid = threadIdx.x;
  if (bid < 8192) {
    int i = (bid * 256 + tid) * 4;
    float4 f = *(const float4*)(x + i);
    uint2 o = {pk2(f.x, f.y), pk2(f.z, f.w)};
    *(uint2*)(xb + i) = o;
  } else if (bid < 8192 + 3072) {
    int tb = bid - 8192;
    int sec = tb >> 10, rem = tb & 1023;
    int h = rem >> 6, sub = rem & 63, ct = sub >> 1, dt = sub & 1;
    const float* W = (sec == 0) ? Wq : (sec == 1) ? Wk : Wv;
    int tx = tid & 31, ty = tid >> 5;
#pragma unroll
    for (int p = 0; p < 4; ++p)
      T[ty + 8 * p][tx] =
          W[((size_t)h * CC + ct * 32 + ty + 8 * p) * DH + dt * 32 + tx];
    __syncthreads();
#pragma unroll
    for (int p = 0; p < 4; ++p) {
      int n = sec * 1024 + h * 64 + dt * 32 + ty + 8 * p;
      Wt[(size_t)n * CC + ct * 32 + tx] = f2bf(T[tx][ty + 8 * p]);
    }
  } else {
    int i = ((bid - 11264) * 256 + tid) * 4;
    float4 f = *(const float4*)(Wo + i);
    uint2 o = {pk2(f.x, f.y), pk2(f.z, f.w)};
    *(uint2*)(Wob + i) = o;
  }
}

// ---------------------------------------------------------------------------
// QKV GEMM, phase-locked pipeline (m201-style T3+T4 schedule):
// C[8192,3072] = xb[8192,1024] @ Wt[3072,1024]^T.
// BM=128 BN=384 BK=32, 512 thr = 8 waves (2M x 4N), wave tile 64x96.
// Grid 8x64 = 512 blocks = exactly 2 full CU-rounds (perfect balance).
// TRIPLE-buffered LDS (96KB): staging during tile t fills slot for t+2, so
// the counted vmcnt(4) at each tile end waits only on loads aged >= 1 full
// tile (~HBM latency already covered) -- never a fresh drain.
// 2 phases per K-tile, 12 MFMA each: {ds_read subtile || issue gloads ->
// barrier -> setprio(1) MFMA setprio(0) -> barrier}.  64B LDS rows (BK=32)
// are bank-conflict-minimal for the b128 fragment reads without swizzle.
// ---------------------------------------------------------------------------
__global__ __launch_bounds__(512, 2) void gemm_qkv(
    const u16* __restrict__ A, const u16* __restrict__ Bt,
    u16* __restrict__ qout, u16* __restrict__ kout, u16* __restrict__ vout) {
  __shared__ u16 As[3 * 128 * 32];  // 24 KB, slot stride 4096 elems
  __shared__ u16 Bs[3 * 384 * 32];  // 72 KB, slot stride 12288 elems

  int tid = threadIdx.x;
  int lane = tid & 63, w = tid >> 6;
  int wr = w >> 2, wc = w & 3;
  int g = lane >> 4, c = lane & 15;
  int m0 = blockIdx.y * 128, n0 = blockIdx.x * 384;

  floatx4 acc[4][6];
#pragma unroll
  for (int i = 0; i < 4; ++i)
#pragma unroll
    for (int j = 0; j < 6; ++j) acc[i][j] = (floatx4){0.f, 0.f, 0.f, 0.f};

  // staging: thread t covers row tid>>2 (of a 128-row unit), col (tid&3)*8
  int arow = tid >> 2, acol = (tid & 3) * 8;
  const u16* Ag = A + (size_t)(m0 + arow) * CC + acol;
  const u16* Bg = Bt + (size_t)(n0 + arow) * CC + acol;
  u16* asd = As + tid * 8;  // + slot offset
  u16* bsd = Bs + tid * 8;  // + slot offset (+ j*4096 per 128-row unit)

  // fragment-read element offsets (per-thread invariant; + slot offset)
  int aro = (wr * 64 + c) * 32 + g * 8;   // + mt*512
  int bro = (wc * 96 + c) * 32 + g * 8;   // + nt*512

  // prologue: stage tile 0 -> slot 0, tile 1 -> slot 1
  gload_lds16(Ag, asd);
  gload_lds16(Bg, bsd);
  gload_lds16(Bg + (size_t)128 * CC, bsd + 4096);
  gload_lds16(Bg + (size_t)256 * CC, bsd + 8192);
  gload_lds16(Ag + 32, asd + 4096);
  gload_lds16(Bg + 32, bsd + 12288);
  gload_lds16(Bg + 32 + (size_t)128 * CC, bsd + 12288 + 4096);
  gload_lds16(Bg + 32 + (size_t)256 * CC, bsd + 12288 + 8192);
  asm volatile("s_waitcnt vmcnt(4)" ::: "memory");  // tile 0 resident
  BAR();

#define QTILE(SCA, SCB, SPA, SPB, T2, STG, VMW)                               \
  {                                                                           \
    short8 af0 = *(const short8*)(As + (SCA) + aro);                          \
    short8 af1 = *(const short8*)(As + (SCA) + aro + 512);                    \
    short8 af2 = *(const short8*)(As + (SCA) + aro + 1024);                   \
    short8 af3 = *(const short8*)(As + (SCA) + aro + 1536);                   \
    short8 bv0 = *(const short8*)(Bs + (SCB) + bro);                          \
    short8 bv1 = *(const short8*)(Bs + (SCB) + bro + 512);                    \
    short8 bv2 = *(const short8*)(Bs + (SCB) + bro + 1024);                   \
    if (STG) {                                                                \
      gload_lds16(Ag + (size_t)(T2) * 32, asd + (SPA));                       \
      gload_lds16(Bg + (size_t)(T2) * 32, bsd + (SPB));                       \
    }                                                                         \
    BAR();                                                                    \
    __builtin_amdgcn_s_setprio(1);                                            \
    acc[0][0] = MFMA_BF16(af0, bv0, acc[0][0], 0, 0, 0);                      \
    acc[0][1] = MFMA_BF16(af0, bv1, acc[0][1], 0, 0, 0);                      \
    acc[0][2] = MFMA_BF16(af0, bv2, acc[0][2], 0, 0, 0);                      \
    acc[1][0] = MFMA_BF16(af1, bv0, acc[1][0], 0, 0, 0);                      \
    acc[1][1] = MFMA_BF16(af1, bv1, acc[1][1], 0, 0, 0);                      \
    acc[1][2] = MFMA_BF16(af1, bv2, acc[1][2], 0, 0, 0);                      \
    acc[2][0] = MFMA_BF16(af2, bv0, acc[2][0], 0, 0, 0);                      \
    acc[2][1] = MFMA_BF16(af2, bv1, acc[2][1], 0, 0, 0);                      \
    acc[2][2] = MFMA_BF16(af2, bv2, acc[2][2], 0, 0, 0);                      \
    acc[3][0] = MFMA_BF16(af3, bv0, acc[3][0], 0, 0, 0);                      \
    acc[3][1] = MFMA_BF16(af3, bv1, acc[3][1], 0, 0, 0);                      \
    acc[3][2] = MFMA_BF16(af3, bv2, acc[3][2], 0, 0, 0);                      \
    __builtin_amdgcn_s_setprio(0);                                            \
    BAR();                                                                    \
    short8 bv3 = *(const short8*)(Bs + (SCB) + bro + 1536);                   \
    short8 bv4 = *(const short8*)(Bs + (SCB) + bro + 2048);                   \
    short8 bv5 = *(const short8*)(Bs + (SCB) + bro + 2560);                   \
    if (STG) {                                                                \
      gload_lds16(Bg + (size_t)(T2) * 32 + (size_t)128 * CC,                  \
                  bsd + (SPB) + 4096);                                        \
      gload_lds16(Bg + (size_t)(T2) * 32 + (size_t)256 * CC,                  \
                  bsd + (SPB) + 8192);                                        \
    }                                                                         \
    BAR();                                                                    \
    __builtin_amdgcn_s_setprio(1);                                            \
    acc[0][3] = MFMA_BF16(af0, bv3, acc[0][3], 0, 0, 0);                      \
    acc[0][4] = MFMA_BF16(af0, bv4, acc[0][4], 0, 0, 0);                      \
    acc[0][5] = MFMA_BF16(af0, bv5, acc[0][5], 0, 0, 0);                      \
    acc[1][3] = MFMA_BF16(af1, bv3, acc[1][3], 0, 0, 0);                      \
    acc[1][4] = MFMA_BF16(af1, bv4, acc[1][4], 0, 0, 0);                      \
    acc[1][5] = MFMA_BF16(af1, bv5, acc[1][5], 0, 0, 0);                      \
    acc[2][3] = MFMA_BF16(af2, bv3, acc[2][3], 0, 0, 0);                      \
    acc[2][4] = MFMA_BF16(af2, bv4, acc[2][4], 0, 0, 0);                      \
    acc[2][5] = MFMA_BF16(af2, bv5, acc[2][5], 0, 0, 0);                      \
    acc[3][3] = MFMA_BF16(af3, bv3, acc[3][3], 0, 0, 0);                      \
    acc[3][4] = MFMA_BF16(af3, bv4, acc[3][4], 0, 0, 0);                      \
    acc[3][5] = MFMA_BF16(af3, bv5, acc[3][5], 0, 0, 0);                      \
    __builtin_amdgcn_s_setprio(0);                                            \
    VMW;                                                                      \
    BAR();                                                                    \
  }

  // slot offsets: cur / next / staging-target (= oldest, freed last tile)
  int scA = 0, snA = 4096, spA = 8192;
  int scB = 0, snB = 12288, spB = 24576;
#pragma unroll 1
  for (int t = 0; t < 30; ++t) {
    QTILE(scA, scB, spA, spB, t + 2, 1,
          asm volatile("s_waitcnt vmcnt(4)" ::: "memory"));
    int ta = scA; scA = snA; snA = spA; spA = ta;
    int tb = scB; scB = snB; snB = spB; spB = tb;
  }
  // t=30: nothing left to stage; drain tile 31's loads (aged 2 tiles)
  QTILE(scA, scB, spA, spB, 0, 0,
        asm volatile("s_waitcnt vmcnt(0)" ::: "memory"));
  {
    int ta = scA; scA = snA; snA = spA; spA = ta;
    int tb = scB; scB = snB; snB = spB; spB = tb;
  }
  // t=31: last tile, no staging, no wait
  QTILE(scA, scB, spA, spB, 0, 0, (void)0);
#undef QTILE

  // epilogue: scatter to q/k/v in [bh][t][d] layout (16-lane d-contiguous)
  int mrow = m0 + wr * 64 + g * 4;
  int ncol = n0 + wc * 96 + c;
#pragma unroll
  for (int nt = 0; nt < 6; ++nt) {
    int n = ncol + nt * 16;
    int sec = n >> 10, h = (n >> 6) & 15, d = n & 63;
    u16* dst = (sec == 0) ? qout : (sec == 1) ? kout : vout;
    float sc = (sec == 0) ? 0.18033688011112042f : 1.f;
    // ^ DH^-0.5 * log2(e): softmax runs in exp2 domain
#pragma unroll
    for (int mt = 0; mt < 4; ++mt) {
#pragma unroll
      for (int r = 0; r < 4; ++r) {
        int m = mrow + mt * 16 + r;
        int b = m >> 11, t = m & 2047;
        dst[(((size_t)(b * HH + h)) * TT + t) * DH + d] =
            f2bf(acc[mt][nt][r] * sc);
      }
    }
  }
}

// ---------------------------------------------------------------------------
// GEMM: C[M,N] = A[M,K] @ Bt[N,K]^T, bf16 in, fp32 accum. m97 pattern.
// (now used only as MODE 1: output projection +bias fp32)
// ---------------------------------------------------------------------------
template <int MODE>
__global__ __launch_bounds__(256) void gemm_bt(
    const u16* __restrict__ A, const u16* __restrict__ Bt, int M, int N, int K,
    u16* __restrict__ qout, u16* __restrict__ kout, u16* __restrict__ vout,
    float* __restrict__ out, const float* __restrict__ bias) {
  __shared__ u16 As[128][64];  // unpadded: required by global_load_lds
  __shared__ u16 Bs[128][64];
  int tid = threadIdx.x;
  int lane = tid & 63, w = tid >> 6;
  int wm = w >> 1, wn = w & 1;
  int g = lane >> 4, c = lane & 15;
  int m0 = blockIdx.y * 128, n0 = blockIdx.x * 128;

  floatx4 acc[4][4];
#pragma unroll
  for (int i = 0; i < 4; ++i)
#pragma unroll
    for (int j = 0; j < 4; ++j) acc[i][j] = (floatx4){0.f, 0.f, 0.f, 0.f};

  int srow = 32 * w + (lane >> 3);
  int scol = (lane & 7) * 8;
  const u16* Ag = A + (size_t)(m0 + srow) * K + scol;
  const u16* Bg = Bt + (size_t)(n0 + srow) * K + scol;
  u16* AsB = &As[32 * w][0];
  u16* BsB = &Bs[32 * w][0];

  for (int k0 = 0; k0 < K; k0 += 64) {
    __syncthreads();
#pragma unroll
    for (int j = 0; j < 4; ++j)
      gload_lds16(Ag + k0 + (size_t)j * 8 * K, AsB + j * 512);
#pragma unroll
    for (int j = 0; j < 4; ++j)
      gload_lds16(Bg + k0 + (size_t)j * 8 * K, BsB + j * 512);
    __syncthreads();
#pragma unroll
    for (int kc = 0; kc < 2; ++kc) {
      short8 af[4], bfv[4];
#pragma unroll
      for (int mt = 0; mt < 4; ++mt)
        af[mt] = *(const short8*)(&As[wm * 64 + mt * 16 + c][kc * 32 + g * 8]);
#pragma unroll
      for (int nt = 0; nt < 4; ++nt)
        bfv[nt] = *(const short8*)(&Bs[wn * 64 + nt * 16 + c][kc * 32 + g * 8]);
#pragma unroll
      for (int mt = 0; mt < 4; ++mt)
#pragma unroll
        for (int nt = 0; nt < 4; ++nt)
          acc[mt][nt] = MFMA_BF16(af[mt], bfv[nt], acc[mt][nt], 0, 0, 0);
    }
  }

#pragma unroll
  for (int mt = 0; mt < 4; ++mt) {
#pragma unroll
    for (int nt = 0; nt < 4; ++nt) {
#pragma unroll
      for (int r = 0; r < 4; ++r) {
        int m = m0 + wm * 64 + mt * 16 + g * 4 + r;  // C-layout: row=(lane>>4)*4+reg
        int n = n0 + wn * 64 + nt * 16 + c;          //           col=lane&15
        float v = acc[mt][nt][r];
        if (MODE == 0) {
          int b = m >> 11, t = m & 2047;
          int sec = n >> 10, h = (n >> 6) & 15, d = n & 63;
          size_t idx = (((size_t)(b * HH + h)) * TT + t) * DH + d;
          if (sec == 0)
            qout[idx] = f2bf(v * 0.18033688011112042f);
          else if (sec == 1)
            kout[idx] = f2bf(v);
          else
            vout[idx] = f2bf(v);
        } else {
          out[(size_t)m * N + n] = v + bias[n];
        }
      }
    }
  }
}

// ---------------------------------------------------------------------------
// V permute-transpose: v[bh][s][d] -> vP[bh][d][tile][u] where
// s = tile*64 + (u&3)*16 + (u>>2)  (i.e. u = 4*(s&15) + ((s>>4)&3)).
// ---------------------------------------------------------------------------
__global__ __launch_bounds__(256) void vtrans(const u16* __restrict__ v,
                                              u16* __restrict__ vP) {
  __shared__ u16 Ld[64][72];
  int tile = blockIdx.x, bh = blockIdx.y, tid = threadIdx.x;
  int row = tid >> 2, col = (tid & 3) * 16;
  const u16* src = v + ((size_t)bh * TT + tile * 64 + row) * DH + col;
  *(uint4*)(&Ld[row][col]) = *(const uint4*)(src);
  *(uint4*)(&Ld[row][col + 8]) = *(const uint4*)(src + 8);
  __syncthreads();
  int d = tid >> 2, u0 = (tid & 3) * 16;
  union { u16 h[16]; uint4 q[2]; } o;
#pragma unroll
  for (int k = 0; k < 16; ++k) {
    int u = u0 + k;
    int s = ((u & 3) << 4) | (u >> 2);
    o.h[k] = Ld[s][d];
  }
  u16* dst = vP + ((size_t)(bh * DH + d)) * TT + tile * 64 + u0;
  *(uint4*)(dst) = o.q[0];
  *(uint4*)(dst + 8) = o.q[1];
}

// ---------------------------------------------------------------------------
// Causal flash with uniform work chunking (LPT order, split heavy q-tiles
// into two key-halves; scale-free softmax partials merge by plain addition).
// ---------------------------------------------------------------------------
__constant__ unsigned char CHUNK_X[24] = {15, 15, 7, 14, 14, 13, 13, 6,
                                          12, 12, 11, 11, 5, 10, 10, 9,
                                          9,  4,  8,  8,  3, 2,  1,  0};
__constant__ unsigned char CHUNK_H[24] = {0, 1, 2, 0, 1, 0, 1, 2, 0, 1, 0, 1,
                                          2, 0, 1, 0, 1, 2, 0, 1, 2, 2, 2, 2};

__global__ __launch_bounds__(256, 4) void flash_attn(
    const u16* __restrict__ q, const u16* __restrict__ k,
    const u16* __restrict__ vP, u16* __restrict__ O,
    float* __restrict__ opart, float* __restrict__ lpart) {
  __shared__ u16 Ks[64][72];     // [s][d]
  __shared__ u16 Vs[64][72];     // [d][u]  (u = permuted s)
  __shared__ u16 Ps[4][32][72];  // per-wave P tile [m][u]

  int tid = threadIdx.x;
  int lane = tid & 63, w = tid >> 6;
  int g = lane >> 4, c = lane & 15;

  int id = blockIdx.x;
  int e = id >> 6, bh = id & 63;
  int x = CHUNK_X[e], hf = CHUNK_H[e];  // hf: 0/1 = key-half, 2 = whole tile
  int sb, se;
  if (hf == 2) {
    sb = 0; se = 2 * x + 2;
  } else {
    int n = x + 1; sb = hf * n; se = sb + n;
  }
  int t0 = x << 7;

  const u16* qb = q + (size_t)bh * TT * DH;
  const u16* kb = k + (size_t)bh * TT * DH;
  const u16* vb = vP + (size_t)bh * DH * TT;

  // Q fragments persistent in registers (A-layout: m=lane&15, k=(lane>>4)*8+j)
  short8 qf[2][2];
#pragma unroll
  for (int mt = 0; mt < 2; ++mt) {
    int qrow = t0 + w * 32 + mt * 16 + c;
#pragma unroll
    for (int kc = 0; kc < 2; ++kc)
      qf[mt][kc] = *(const short8*)(qb + (size_t)qrow * DH + kc * 32 + g * 8);
  }

  const floatx4 zf = {0.f, 0.f, 0.f, 0.f};
  const short8 onesf = {(short)0x3F80, (short)0x3F80, (short)0x3F80,
                        (short)0x3F80, (short)0x3F80, (short)0x3F80,
                        (short)0x3F80, (short)0x3F80};  // bf16 1.0 x8

  floatx4 oacc[2][4];
#pragma unroll
  for (int mt = 0; mt < 2; ++mt)
#pragma unroll
    for (int nt = 0; nt < 4; ++nt) oacc[mt][nt] = zf;
  floatx4 lacc[2];
  lacc[0] = zf;
  lacc[1] = zf;

  // staging: row = tid>>2 (0..63), col base = (tid&3)*16, 2x16B per tensor
  int srow = tid >> 2, scol = (tid & 3) * 16;
  const u16* kbase = kb + (size_t)srow * DH + scol;
  const u16* vbase = vb + (size_t)srow * TT + scol;  // vP rows: [d][t-contig]

  // preload iter sb
  uint4 kr0 = *(const uint4*)(kbase + (size_t)(sb << 6) * DH);
  uint4 kr1 = *(const uint4*)(kbase + (size_t)(sb << 6) * DH + 8);
  uint4 vr0 = *(const uint4*)(vbase + (sb << 6));
  uint4 vr1 = *(const uint4*)(vbase + (sb << 6) + 8);

  int nfull = 2 * x;  // iters >= nfull need the causal mask
  int wmax = t0 + w * 32 + 31;
  for (int it = sb; it < se; ++it) {
    int s0 = it << 6;
    __syncthreads();  // all waves done reading prev tiles
    *(uint4*)(&Ks[srow][scol]) = kr0;
    *(uint4*)(&Ks[srow][scol + 8]) = kr1;
    *(uint4*)(&Vs[srow][scol]) = vr0;
    *(uint4*)(&Vs[srow][scol + 8]) = vr1;
    __syncthreads();
    if (it + 1 < se) {  // prefetch next tile: latency hidden by compute
      size_t koff = (size_t)((it + 1) << 6) * DH;
      int voff = (it + 1) << 6;
      kr0 = *(const uint4*)(kbase + koff);
      kr1 = *(const uint4*)(kbase + koff + 8);
      vr0 = *(const uint4*)(vbase + voff);
      vr1 = *(const uint4*)(vbase + voff + 8);
    }
    if (s0 > wmax) continue;  // wave-uniform: tile fully masked (last iter)
    bool masked = (it >= nfull);

    // S = Q K^T ; kf shared across both m-tiles; kc=0 uses zero C-operand
    floatx4 z[2][4];
#pragma unroll
    for (int n = 0; n < 4; ++n) {
      short8 kf = *(const short8*)(&Ks[n * 16 + c][g * 8]);
      z[0][n] = MFMA_BF16(qf[0][0], kf, zf, 0, 0, 0);
      z[1][n] = MFMA_BF16(qf[1][0], kf, zf, 0, 0, 0);
    }
#pragma unroll
    for (int n = 0; n < 4; ++n) {
      short8 kf = *(const short8*)(&Ks[n * 16 + c][32 + g * 8]);
      z[0][n] = MFMA_BF16(qf[0][1], kf, z[0][n], 0, 0, 0);
      z[1][n] = MFMA_BF16(qf[1][1], kf, z[1][n], 0, 0, 0);
    }

    // softmax (no offset: uniform scale cancels in the final division);
    // P packed to bf16 by v_perm truncation, b64 stores
#pragma unroll
    for (int mt = 0; mt < 2; ++mt) {
      int qr = t0 + w * 32 + mt * 16 + g * 4;
#pragma unroll
      for (int r = 0; r < 4; ++r) {
        float p0 = exp2f(z[mt][0][r]);
        float p1 = exp2f(z[mt][1][r]);
        float p2 = exp2f(z[mt][2][r]);
        float p3 = exp2f(z[mt][3][r]);
        if (masked) {
          if (s0 + c > qr + r) p0 = 0.f;
          if (s0 + 16 + c > qr + r) p1 = 0.f;
          if (s0 + 32 + c > qr + r) p2 = 0.f;
          if (s0 + 48 + c > qr + r) p3 = 0.f;
        }
        // u-layout: s = n*16+c -> u = 4c+n; 4 values contiguous at u0=4c
        uint2 pk = {pktrunc(p0, p1), pktrunc(p2, p3)};
        *(uint2*)(&Ps[w][mt * 16 + g * 4 + r][4 * c]) = pk;
      }
    }

    // PV + lsum-by-MFMA: vf shared across both m-tiles (intra-wave LDS)
#pragma unroll
    for (int kc = 0; kc < 2; ++kc) {
      short8 pf0 = *(const short8*)(&Ps[w][c][kc * 32 + g * 8]);
      short8 pf1 = *(const short8*)(&Ps[w][16 + c][kc * 32 + g * 8]);
      lacc[0] = MFMA_BF16(pf0, onesf, lacc[0], 0, 0, 0);
      lacc[1] = MFMA_BF16(pf1, onesf, lacc[1], 0, 0, 0);
#pragma unroll
      for (int nt = 0; nt < 4; ++nt) {
        short8 vf = *(const short8*)(&Vs[nt * 16 + c][kc * 32 + g * 8]);
        oacc[0][nt] = MFMA_BF16(pf0, vf, oacc[0][nt], 0, 0, 0);
        oacc[1][nt] = MFMA_BF16(pf1, vf, oacc[1][nt], 0, 0, 0);
      }
    }
  }

  // epilogue: lacc[mt][r] already holds the full row-sum (replicated over c)
  int b = bh >> 4, h = bh & 15;
  if (hf == 2) {
    // light chunk: normalize and write bf16 directly
#pragma unroll
    for (int mt = 0; mt < 2; ++mt) {
      float inv[4];
#pragma unroll
      for (int r = 0; r < 4; ++r) inv[r] = 1.f / lacc[mt][r];
#pragma unroll
      for (int nt = 0; nt < 4; ++nt)
#pragma unroll
        for (int r = 0; r < 4; ++r) {
          int trow = t0 + w * 32 + mt * 16 + g * 4 + r;
          O[((size_t)b * TT + trow) * CC + h * DH + nt * 16 + c] =
              f2bf(oacc[mt][nt][r] * inv[r]);
        }
    }
  } else {
    // heavy half: store raw fp32 partials; merge_heavy combines
    float* os = opart + ((size_t)hf * 65536 + (size_t)bh * 1024) * 64;
    float* ls = lpart + (size_t)hf * 65536 + (size_t)bh * 1024;
#pragma unroll
    for (int mt = 0; mt < 2; ++mt) {
      int r0 = t0 - 1024 + w * 32 + mt * 16 + g * 4;  // local heavy-row base
#pragma unroll
      for (int nt = 0; nt < 4; ++nt)
#pragma unroll
        for (int r = 0; r < 4; ++r)
          os[(size_t)(r0 + r) * 64 + nt * 16 + c] = oacc[mt][nt][r];
      if (c == 0)
#pragma unroll
        for (int r = 0; r < 4; ++r) ls[r0 + r] = lacc[mt][r];
    }
  }
}

// ---------------------------------------------------------------------------
// Merge the two key-half partials for heavy rows (t in [1024, 2048)):
// Ow = (o0 + o1) / (l0 + l1). ~42 MB traffic, memory-bound.
// ---------------------------------------------------------------------------
__global__ __launch_bounds__(256) void merge_heavy(
    const float* __restrict__ op, const float* __restrict__ lp,
    u16* __restrict__ O) {
  int gid = blockIdx.x * 256 + threadIdx.x;  // 64 bh * 1024 rows * 16 chunks
  int dq = gid & 15;                         // float4 chunk within d=64
  int row = gid >> 4;                        // bh*1024 + lr
  float4 a = *(const float4*)(op + (size_t)row * 64 + dq * 4);
  float4 b = *(const float4*)(op + ((size_t)row + 65536) * 64 + dq * 4);
  float inv = 1.f / (lp[row] + lp[row + 65536]);
  int bh = row >> 10, lr = row & 1023;
  int bb = bh >> 4, h = bh & 15;
  u16* dst = O + ((size_t)bb * TT + 1024 + lr) * CC + h * DH + dq * 4;
  uint2 o = {pk2((a.x + b.x) * inv, (a.y + b.y) * inv),
             pk2((a.z + b.z) * inv, (a.w + b.w) * inv)};
  *(uint2*)dst = o;
}

// ---------------------------------------------------------------------------
extern "C" void kernel_launch(void* const* d_in, const int* in_sizes, int n_in,
                              void* d_out, int out_size, void* d_ws,
                              size_t ws_size, hipStream_t stream) {
  const float* x = (const float*)d_in[0];
  const float* Wq = (const float*)d_in[1];
  const float* Wk = (const float*)d_in[2];
  const float* Wv = (const float*)d_in[3];
  const float* Wo = (const float*)d_in[4];
  const float* bo = (const float*)d_in[5];
  float* out = (float*)d_out;

  u16* ws = (u16*)d_ws;
  u16* xb = ws;                        // 8388608  (reused as Ow after QKV GEMM)
  u16* Wt = xb + 8388608;              // 3145728  (dead after gemm_qkv: lpart)
  u16* Wob = Wt + 3145728;             // 1048576
  u16* qw = Wob + 1048576;             // 8388608
  u16* kw = qw + 8388608;              // 8388608
  u16* vw = kw + 8388608;              // 8388608 ([bh][t][d], coalesced)
  u16* vP = vw + 8388608;              // 8388608 (permuted [bh][d][tile][u])
  u16* Ow = xb;                        // alias: xb dead after gemm_qkv
  float* opart = (float*)d_out;        // dead until gemm<1>
  float* lpart = (float*)Wt;           // Wt dead after gemm_qkv

  convert_kernel<<<12288, 256, 0, stream>>>(x, Wq, Wk, Wv, Wo, xb, Wt, Wob);

  gemm_qkv<<<dim3(NQKV / 384, MM / 128), 512, 0, stream>>>(
      xb, Wt, qw, kw, vw);

  vtrans<<<dim3(TT / 64, BB * HH), 256, 0, stream>>>(vw, vP);

  flash_attn<<<dim3(1536), 256, 0, stream>>>(qw, kw, vP, Ow, opart, lpart);

  merge_heavy<<<dim3(4096), 256, 0, stream>>>(opart, lpart, Ow);

  gemm_bt<1><<<dim3(CC / 128, MM / 128), 256, 0, stream>>>(
      Ow, Wob, MM, CC, CC, nullptr, nullptr, nullptr, out, bo);
}